// Round 8
// baseline (293.816 us; speedup 1.0000x reference)
//
#include <hip/hip_runtime.h>
#include <stdint.h>

#define NPTS        16384
#define BATCH       8
#define QPB         128                     // queries per block (4 waves * 32)
#define QBLKS       (NPTS / QPB)            // 128
#define CHAM_BLOCKS (BATCH * 2 * QBLKS)     // 2048
#define NOISE_N     (BATCH * NPTS * 3)      // 393216
#define NOISE_V4    (NOISE_N / 4)           // 98304
#define NPTS_TOT    (BATCH * NPTS)          // 131072
#define PACK_BLOCKS (NPTS_TOT / 256)        // 512
#define REF_ITERS   (NPTS * 8 / 1024)       // 128 (1 KB of packed refs per iter)

// workspace layout (bytes)
#define WS_NOISE_PART 0                     // 512 floats
#define WS_CHAM_PART  4096                  // 2048 floats
#define WS_TICKET     12288                 // 1 uint
#define WS_PK_PRED    16384
#define WS_PK_TARG    (WS_PK_PRED + 8 * NPTS_TOT)
#define WS_R_PRED     (WS_PK_TARG + 8 * NPTS_TOT)
#define WS_R_TARG     (WS_R_PRED + 4 * NPTS_TOT)

using halfx4 = __attribute__((ext_vector_type(4))) _Float16;
using intx4  = __attribute__((ext_vector_type(4))) int;

__device__ __forceinline__ unsigned int f2h(float f) {
  union { _Float16 h; unsigned short s; } v; v.h = (_Float16)f; return v.s;
}
__device__ __forceinline__ float h2f(unsigned short s) {
  union { _Float16 h; unsigned short u; } v; v.u = s; return (float)v.h;
}

// One 4-MFMA group, software-pipelined across TWO pinned banks
// (v[32:47], v[48:63]). Each MFMA's ~18-cycle dest->VALU-read hazard is
// covered by the OTHER bank's min3 tree instead of s_nop (R7 post-mortem:
// 72 cyc/group of nop cushions were ~32% of per-wave group time). Residual
// nops: head 2 (VALU-write -> MFMA-read on operands), 16 after the first
// MFMA pair, 1+2 interior nudges = ~21 cyc/group.
__device__ __forceinline__ void mfma_group(halfx4 a0, halfx4 a1, halfx4 b0, halfx4 b1,
                                           float& m0, float& m1, float& m2, float& m3) {
  asm("s_nop 1\n\t"
      "v_mfma_f32_32x32x8_f16 v[32:47], %4, %6, 0\n\t"
      "v_mfma_f32_32x32x8_f16 v[48:63], %4, %7, 0\n\t"
      "s_nop 7\n\t"
      "s_nop 7\n\t"
      "v_min3_f32 v32, v32, v33, v34\n\t"   // m0 tree (bank0)
      "v_min3_f32 v35, v35, v36, v37\n\t"
      "v_min3_f32 v38, v38, v39, v40\n\t"
      "v_min3_f32 v41, v41, v42, v43\n\t"
      "v_min3_f32 v44, v44, v45, v46\n\t"
      "v_min3_f32 v32, v32, v35, v38\n\t"
      "v_min3_f32 v41, v41, v44, v47\n\t"
      "v_min3_f32 %0, %0, v32, v41\n\t"
      "v_mfma_f32_32x32x8_f16 v[32:47], %5, %6, 0\n\t"
      "v_min3_f32 v48, v48, v49, v50\n\t"   // m1 tree (bank1); covers MFMA above
      "v_min3_f32 v51, v51, v52, v53\n\t"
      "v_min3_f32 v54, v54, v55, v56\n\t"
      "v_min3_f32 v57, v57, v58, v59\n\t"
      "v_min3_f32 v60, v60, v61, v62\n\t"
      "v_min3_f32 v48, v48, v51, v54\n\t"
      "v_min3_f32 v57, v57, v60, v63\n\t"
      "v_min3_f32 %1, %1, v48, v57\n\t"
      "v_mfma_f32_32x32x8_f16 v[48:63], %5, %7, 0\n\t"
      "s_nop 0\n\t"
      "v_min3_f32 v32, v32, v33, v34\n\t"   // m2 tree (bank0); covers MFMA above
      "v_min3_f32 v35, v35, v36, v37\n\t"
      "v_min3_f32 v38, v38, v39, v40\n\t"
      "v_min3_f32 v41, v41, v42, v43\n\t"
      "v_min3_f32 v44, v44, v45, v46\n\t"
      "v_min3_f32 v32, v32, v35, v38\n\t"
      "v_min3_f32 v41, v41, v44, v47\n\t"
      "v_min3_f32 %2, %2, v32, v41\n\t"
      "s_nop 1\n\t"
      "v_min3_f32 v48, v48, v49, v50\n\t"   // m3 tree (bank1)
      "v_min3_f32 v51, v51, v52, v53\n\t"
      "v_min3_f32 v54, v54, v55, v56\n\t"
      "v_min3_f32 v57, v57, v58, v59\n\t"
      "v_min3_f32 v60, v60, v61, v62\n\t"
      "v_min3_f32 v48, v48, v51, v54\n\t"
      "v_min3_f32 v57, v57, v60, v63\n\t"
      "v_min3_f32 %3, %3, v48, v57"
      : "+v"(m0), "+v"(m1), "+v"(m2), "+v"(m3)
      : "v"(a0), "v"(a1), "v"(b0), "v"(b1)
      : "v32","v33","v34","v35","v36","v37","v38","v39",
        "v40","v41","v42","v43","v44","v45","v46","v47",
        "v48","v49","v50","v51","v52","v53","v54","v55",
        "v56","v57","v58","v59","v60","v61","v62","v63");
}

// ---------------- fused pack (f32 xyz -> f16 {x,y,z,s} + f32 r) + noise L1 ----------------
__global__ void pack_noise_kernel(const float* __restrict__ pred,
                                  const float* __restrict__ targ,
                                  const float4* __restrict__ na,
                                  const float4* __restrict__ nb,
                                  ushort4* __restrict__ pk_pred,
                                  ushort4* __restrict__ pk_targ,
                                  float* __restrict__ r_pred,
                                  float* __restrict__ r_targ,
                                  float* __restrict__ part,
                                  unsigned int* __restrict__ ticket) {
  int i = blockIdx.x * 256 + threadIdx.x;
  if (i == 0) *ticket = 0u;                 // reset chamfer completion counter
  {
    float x = pred[3*i+0], y = pred[3*i+1], z = pred[3*i+2];
    float s = __builtin_fmaf(x, x, __builtin_fmaf(y, y, z*z));
    pk_pred[i] = make_ushort4((unsigned short)f2h(x), (unsigned short)f2h(y),
                              (unsigned short)f2h(z), (unsigned short)f2h(s));
    r_pred[i] = s;
  }
  {
    float x = targ[3*i+0], y = targ[3*i+1], z = targ[3*i+2];
    float s = __builtin_fmaf(x, x, __builtin_fmaf(y, y, z*z));
    pk_targ[i] = make_ushort4((unsigned short)f2h(x), (unsigned short)f2h(y),
                              (unsigned short)f2h(z), (unsigned short)f2h(s));
    r_targ[i] = s;
  }
  // noise L1 over float4-packed elements (98304 of them < 131072 threads)
  float sn = 0.f;
  if (i < NOISE_V4) {
    float4 pa = na[i], pb = nb[i];
    sn = fabsf(pa.x-pb.x) + fabsf(pa.y-pb.y) + fabsf(pa.z-pb.z) + fabsf(pa.w-pb.w);
  }
  for (int o = 1; o < 64; o <<= 1) sn += __shfl_xor(sn, o);
  __shared__ float ws4[4];
  int lane = threadIdx.x & 63, wv = threadIdx.x >> 6;
  if (lane == 0) ws4[wv] = sn;
  __syncthreads();
  if (threadIdx.x == 0) part[blockIdx.x] = ws4[0] + ws4[1] + ws4[2] + ws4[3];
}

// ---------------- chamfer main kernel (+ fused final reduce via ticket) ----------------
__global__ __launch_bounds__(256, 8)
void chamfer_kernel(const ushort4* __restrict__ pk_pred,
                    const ushort4* __restrict__ pk_targ,
                    const float* __restrict__ r_pred,
                    const float* __restrict__ r_targ,
                    float* __restrict__ part,
                    const float* __restrict__ part_noise,
                    unsigned int* __restrict__ ticket,
                    float* __restrict__ out) {
  __shared__ float wsum[4];
  __shared__ float flagv;

  const int tid  = threadIdx.x;
  const int lane = tid & 63;
  const int wv   = tid >> 6;
  const int col  = lane & 31;

  const int blk  = blockIdx.x;
  const int qblk = blk & (QBLKS - 1);
  const int bd   = blk >> 7;
  const int dir  = bd & 1;
  const int b    = bd >> 1;

  const ushort4* qpk = dir ? pk_targ : pk_pred;
  const float*   qr  = dir ? r_targ  : r_pred;
  const ushort4* ref = dir ? pk_pred : pk_targ;
  qpk += b * NPTS; qr += b * NPTS; ref += b * NPTS;

  // ---- B fragments (queries). 32x32x8: B[k][col], lane l holds col=l&31,
  // k = 4*(l>>5)+e (e=0..3, reg r packs e=2r,2r+1). Variant 0 is nonzero at
  // k=0..3 (lanes <32 hold the query [-2x,-2y,-2z,1]); variant 1 at k=4..7.
  const int q = qblk * QPB + wv * 32 + col;
  ushort4 qt = qpk[q];                       // both halves load their column's query
  unsigned int nx = f2h(-2.f * h2f(qt.x));
  unsigned int ny = f2h(-2.f * h2f(qt.y));
  unsigned int nz = f2h(-2.f * h2f(qt.z));
  unsigned int lo = (ny << 16) | nx;
  unsigned int hi = (0x3C00u << 16) | nz;    // [nz, 1.0f16]
  const bool hh = (lane >= 32);

  union BF { halfx4 v; unsigned int u[2]; };
  BF fb0, fb1;
  fb0.u[0] = hh ? 0u : lo; fb0.u[1] = hh ? 0u : hi;
  fb1.u[0] = hh ? lo : 0u; fb1.u[1] = hh ? hi : 0u;

  // A fragments (refs): lane l holds row=l&31, k=4*(l>>5)+e -> one packed
  // ref per halfx4. The 16B/lane load covers 2 refs = 2 A fragments; with
  // 2 B variants each, the 4 MFMA of a group cover all 128 refs of 1 KB.
  union AF { intx4 i; halfx4 h[2]; };

  const char* rbase = (const char*)ref + lane * 16;
  float m0 = 1e30f, m1 = 1e30f, m2 = 1e30f, m3 = 1e30f;

  // depth-2 prefetch rotation; copy-then-reload keeps ~2 groups (~240 cyc)
  // of L2-latency coverage ahead of each consumption.
  intx4 pA = *(const intx4*)(rbase + 0 * 1024);
  intx4 pB = *(const intx4*)(rbase + 1 * 1024);

  for (int it = 0; it < REF_ITERS; it += 2) {
    {
      AF fa; fa.i = pA;
      pA = *(const intx4*)(rbase + (size_t)(((it + 2) & (REF_ITERS - 1)) * 1024));
      mfma_group(fa.h[0], fa.h[1], fb0.v, fb1.v, m0, m1, m2, m3);
    }
    {
      AF fa; fa.i = pB;
      pB = *(const intx4*)(rbase + (size_t)(((it + 3) & (REF_ITERS - 1)) * 1024));
      mfma_group(fa.h[0], fa.h[1], fb0.v, fb1.v, m0, m1, m2, m3);
    }
  }

  float m = fminf(fminf(m0, m1), fminf(m2, m3));

  // lanes l and l^32 cover complementary rows for the same query column
  m = fminf(m, __shfl_xor(m, 32));
  float rq = qr[q];
  float dmin = fmaxf(rq + m, 0.f);
  float v = (lane < 32) ? dmin : 0.f;
  for (int o = 1; o < 32; o <<= 1) v += __shfl_xor(v, o);
  if (lane == 0) wsum[wv] = v;
  __syncthreads();

  if (tid == 0) {
    // publish this block's partial with a device-scope atomic (cross-XCD
    // visible), then take a completion ticket.
    atomicExch(&part[blk], wsum[0] + wsum[1] + wsum[2] + wsum[3]);
    __threadfence();
    unsigned int t = atomicAdd(ticket, 1u);
    flagv = (t == CHAM_BLOCKS - 1) ? 1.f : 0.f;
  }
  __syncthreads();

  if (flagv != 0.f) {
    // last block performs the final reduction (replaces final_kernel).
    float s = 0.f;
    for (int i = tid; i < PACK_BLOCKS; i += 256) s += part_noise[i];   // prior kernel: plain loads ok
    float c = 0.f;
    for (int i = tid; i < CHAM_BLOCKS; i += 256) c += atomicAdd(&part[i], 0.f);  // coherent read
    float acc = s * (1.f / NOISE_N) + 0.1f * c * (1.f / NPTS_TOT);
    for (int o = 1; o < 64; o <<= 1) acc += __shfl_xor(acc, o);
    __syncthreads();
    if (lane == 0) wsum[wv] = acc;
    __syncthreads();
    if (tid == 0) out[0] = wsum[0] + wsum[1] + wsum[2] + wsum[3];
  }
}

extern "C" void kernel_launch(void* const* d_in, const int* in_sizes, int n_in,
                              void* d_out, int out_size, void* d_ws, size_t ws_size,
                              hipStream_t stream) {
  const float* pn = (const float*)d_in[0];
  const float* an = (const float*)d_in[1];
  const float* pp = (const float*)d_in[2];
  const float* tp = (const float*)d_in[3];

  char* ws = (char*)d_ws;
  float*        noise_part = (float*)(ws + WS_NOISE_PART);
  float*        cham_part  = (float*)(ws + WS_CHAM_PART);
  unsigned int* ticket     = (unsigned int*)(ws + WS_TICKET);
  ushort4*      pk_pred    = (ushort4*)(ws + WS_PK_PRED);
  ushort4*      pk_targ    = (ushort4*)(ws + WS_PK_TARG);
  float*        r_pred     = (float*)(ws + WS_R_PRED);
  float*        r_targ     = (float*)(ws + WS_R_TARG);

  pack_noise_kernel<<<PACK_BLOCKS, 256, 0, stream>>>(pp, tp, (const float4*)pn, (const float4*)an,
                                                     pk_pred, pk_targ, r_pred, r_targ,
                                                     noise_part, ticket);
  chamfer_kernel<<<CHAM_BLOCKS, 256, 0, stream>>>(pk_pred, pk_targ, r_pred, r_targ,
                                                  cham_part, noise_part, ticket, (float*)d_out);
}

// Round 9
// 158.841 us; speedup vs baseline: 1.8497x; 1.8497x over previous
//
#include <hip/hip_runtime.h>
#include <stdint.h>

#define NPTS        16384
#define BATCH       8
#define QPB         128                     // queries per block (4 waves * 32)
#define QBLKS       (NPTS / QPB)            // 128
#define CHAM_BLOCKS (BATCH * 2 * QBLKS)     // 2048
#define NOISE_N     (BATCH * NPTS * 3)      // 393216
#define NOISE_V4    (NOISE_N / 4)           // 98304
#define NPTS_TOT    (BATCH * NPTS)          // 131072
#define PACK_BLOCKS (NPTS_TOT / 256)        // 512
#define REF_ITERS   (NPTS * 8 / 1024)       // 128 (1 KB of packed refs per iter)

// workspace layout (bytes)
#define WS_NOISE_PART 0                     // 512 floats
#define WS_CHAM_PART  4096                  // 2048 floats
#define WS_PK_PRED    16384
#define WS_PK_TARG    (WS_PK_PRED + 8 * NPTS_TOT)
#define WS_R_PRED     (WS_PK_TARG + 8 * NPTS_TOT)
#define WS_R_TARG     (WS_R_PRED + 4 * NPTS_TOT)

using halfx4 = __attribute__((ext_vector_type(4))) _Float16;
using intx4  = __attribute__((ext_vector_type(4))) int;

__device__ __forceinline__ unsigned int f2h(float f) {
  union { _Float16 h; unsigned short s; } v; v.h = (_Float16)f; return v.s;
}
__device__ __forceinline__ float h2f(unsigned short s) {
  union { _Float16 h; unsigned short u; } v; v.u = s; return (float)v.h;
}

// One 4-MFMA group, software-pipelined across TWO pinned banks
// (v[32:47], v[48:63]). Each MFMA's ~18-cycle dest->VALU-read hazard is
// covered by the OTHER bank's min3 tree instead of s_nop (R7: 72 cyc/group
// of nop cushions). R8 lesson: this 32-reg pinned footprint REQUIRES the
// 128-reg budget of (256,4) -- at (256,8) the allocator spills (470 MB
// scratch writeback). Residual nops ~21 cyc/group.
__device__ __forceinline__ void mfma_group(halfx4 a0, halfx4 a1, halfx4 b0, halfx4 b1,
                                           float& m0, float& m1, float& m2, float& m3) {
  asm("s_nop 1\n\t"
      "v_mfma_f32_32x32x8_f16 v[32:47], %4, %6, 0\n\t"
      "v_mfma_f32_32x32x8_f16 v[48:63], %4, %7, 0\n\t"
      "s_nop 7\n\t"
      "s_nop 7\n\t"
      "v_min3_f32 v32, v32, v33, v34\n\t"   // m0 tree (bank0)
      "v_min3_f32 v35, v35, v36, v37\n\t"
      "v_min3_f32 v38, v38, v39, v40\n\t"
      "v_min3_f32 v41, v41, v42, v43\n\t"
      "v_min3_f32 v44, v44, v45, v46\n\t"
      "v_min3_f32 v32, v32, v35, v38\n\t"
      "v_min3_f32 v41, v41, v44, v47\n\t"
      "v_min3_f32 %0, %0, v32, v41\n\t"
      "v_mfma_f32_32x32x8_f16 v[32:47], %5, %6, 0\n\t"
      "v_min3_f32 v48, v48, v49, v50\n\t"   // m1 tree (bank1); covers MFMA above
      "v_min3_f32 v51, v51, v52, v53\n\t"
      "v_min3_f32 v54, v54, v55, v56\n\t"
      "v_min3_f32 v57, v57, v58, v59\n\t"
      "v_min3_f32 v60, v60, v61, v62\n\t"
      "v_min3_f32 v48, v48, v51, v54\n\t"
      "v_min3_f32 v57, v57, v60, v63\n\t"
      "v_min3_f32 %1, %1, v48, v57\n\t"
      "v_mfma_f32_32x32x8_f16 v[48:63], %5, %7, 0\n\t"
      "s_nop 0\n\t"
      "v_min3_f32 v32, v32, v33, v34\n\t"   // m2 tree (bank0); covers MFMA above
      "v_min3_f32 v35, v35, v36, v37\n\t"
      "v_min3_f32 v38, v38, v39, v40\n\t"
      "v_min3_f32 v41, v41, v42, v43\n\t"
      "v_min3_f32 v44, v44, v45, v46\n\t"
      "v_min3_f32 v32, v32, v35, v38\n\t"
      "v_min3_f32 v41, v41, v44, v47\n\t"
      "v_min3_f32 %2, %2, v32, v41\n\t"
      "s_nop 1\n\t"
      "v_min3_f32 v48, v48, v49, v50\n\t"   // m3 tree (bank1)
      "v_min3_f32 v51, v51, v52, v53\n\t"
      "v_min3_f32 v54, v54, v55, v56\n\t"
      "v_min3_f32 v57, v57, v58, v59\n\t"
      "v_min3_f32 v60, v60, v61, v62\n\t"
      "v_min3_f32 v48, v48, v51, v54\n\t"
      "v_min3_f32 v57, v57, v60, v63\n\t"
      "v_min3_f32 %3, %3, v48, v57"
      : "+v"(m0), "+v"(m1), "+v"(m2), "+v"(m3)
      : "v"(a0), "v"(a1), "v"(b0), "v"(b1)
      : "v32","v33","v34","v35","v36","v37","v38","v39",
        "v40","v41","v42","v43","v44","v45","v46","v47",
        "v48","v49","v50","v51","v52","v53","v54","v55",
        "v56","v57","v58","v59","v60","v61","v62","v63");
}

// ---------------- fused pack (f32 xyz -> f16 {x,y,z,s} + f32 r) + noise L1 ----------------
__global__ void pack_noise_kernel(const float* __restrict__ pred,
                                  const float* __restrict__ targ,
                                  const float4* __restrict__ na,
                                  const float4* __restrict__ nb,
                                  ushort4* __restrict__ pk_pred,
                                  ushort4* __restrict__ pk_targ,
                                  float* __restrict__ r_pred,
                                  float* __restrict__ r_targ,
                                  float* __restrict__ part) {
  int i = blockIdx.x * 256 + threadIdx.x;
  {
    float x = pred[3*i+0], y = pred[3*i+1], z = pred[3*i+2];
    float s = __builtin_fmaf(x, x, __builtin_fmaf(y, y, z*z));
    pk_pred[i] = make_ushort4((unsigned short)f2h(x), (unsigned short)f2h(y),
                              (unsigned short)f2h(z), (unsigned short)f2h(s));
    r_pred[i] = s;
  }
  {
    float x = targ[3*i+0], y = targ[3*i+1], z = targ[3*i+2];
    float s = __builtin_fmaf(x, x, __builtin_fmaf(y, y, z*z));
    pk_targ[i] = make_ushort4((unsigned short)f2h(x), (unsigned short)f2h(y),
                              (unsigned short)f2h(z), (unsigned short)f2h(s));
    r_targ[i] = s;
  }
  // noise L1 over float4-packed elements (98304 of them < 131072 threads)
  float sn = 0.f;
  if (i < NOISE_V4) {
    float4 pa = na[i], pb = nb[i];
    sn = fabsf(pa.x-pb.x) + fabsf(pa.y-pb.y) + fabsf(pa.z-pb.z) + fabsf(pa.w-pb.w);
  }
  for (int o = 1; o < 64; o <<= 1) sn += __shfl_xor(sn, o);
  __shared__ float ws4[4];
  int lane = threadIdx.x & 63, wv = threadIdx.x >> 6;
  if (lane == 0) ws4[wv] = sn;
  __syncthreads();
  if (threadIdx.x == 0) part[blockIdx.x] = ws4[0] + ws4[1] + ws4[2] + ws4[3];
}

// ---------------- chamfer main kernel ----------------
// 32x32x8 f16 MFMA in a two-bank pipelined blob; refs from L2 with a
// 4-deep prefetch rotation. (256,4): 128-reg budget so the 32 pinned
// scratch regs + ~45 allocator regs fit with NO spill; the pipelined blob
// keeps the MFMA pipe fed even at 4 waves/SIMD.
__global__ __launch_bounds__(256, 4)
void chamfer_kernel(const ushort4* __restrict__ pk_pred,
                    const ushort4* __restrict__ pk_targ,
                    const float* __restrict__ r_pred,
                    const float* __restrict__ r_targ,
                    float* __restrict__ part) {
  __shared__ float wsum[4];

  const int tid  = threadIdx.x;
  const int lane = tid & 63;
  const int wv   = tid >> 6;
  const int col  = lane & 31;

  const int blk  = blockIdx.x;
  const int qblk = blk & (QBLKS - 1);
  const int bd   = blk >> 7;
  const int dir  = bd & 1;
  const int b    = bd >> 1;

  const ushort4* qpk = dir ? pk_targ : pk_pred;
  const float*   qr  = dir ? r_targ  : r_pred;
  const ushort4* ref = dir ? pk_pred : pk_targ;
  qpk += b * NPTS; qr += b * NPTS; ref += b * NPTS;

  // ---- B fragments (queries). 32x32x8: B[k][col], lane l holds col=l&31,
  // k = 4*(l>>5)+e (e=0..3, reg r packs e=2r,2r+1). Variant 0 is nonzero at
  // k=0..3 (lanes <32 hold the query [-2x,-2y,-2z,1]); variant 1 at k=4..7.
  const int q = qblk * QPB + wv * 32 + col;
  ushort4 qt = qpk[q];                       // both halves load their column's query
  unsigned int nx = f2h(-2.f * h2f(qt.x));
  unsigned int ny = f2h(-2.f * h2f(qt.y));
  unsigned int nz = f2h(-2.f * h2f(qt.z));
  unsigned int lo = (ny << 16) | nx;
  unsigned int hi = (0x3C00u << 16) | nz;    // [nz, 1.0f16]
  const bool hh = (lane >= 32);

  union BF { halfx4 v; unsigned int u[2]; };
  BF fb0, fb1;
  fb0.u[0] = hh ? 0u : lo; fb0.u[1] = hh ? 0u : hi;
  fb1.u[0] = hh ? lo : 0u; fb1.u[1] = hh ? hi : 0u;

  // A fragments (refs): lane l holds row=l&31, k=4*(l>>5)+e -> one packed
  // ref per halfx4. The 16B/lane load covers 2 refs = 2 A fragments; with
  // 2 B variants each, the 4 MFMA of a group cover all 128 refs of 1 KB.
  union AF { intx4 i; halfx4 h[2]; };

  const char* rbase = (const char*)ref + lane * 16;
  float m0 = 1e30f, m1 = 1e30f, m2 = 1e30f, m3 = 1e30f;

  // 4-deep prefetch rotation (named vars -> registers, rule #20).
  intx4 pA = *(const intx4*)(rbase + 0 * 1024);
  intx4 pB = *(const intx4*)(rbase + 1 * 1024);
  intx4 pC = *(const intx4*)(rbase + 2 * 1024);
  intx4 pD = *(const intx4*)(rbase + 3 * 1024);

#define STEP(P, k)                                                          \
  {                                                                         \
    AF fa; fa.i = P;                                                        \
    P = *(const intx4*)(rbase + (size_t)(((it + (k) + 4) & (REF_ITERS - 1)) * 1024)); \
    mfma_group(fa.h[0], fa.h[1], fb0.v, fb1.v, m0, m1, m2, m3);             \
  }

  for (int it = 0; it < REF_ITERS; it += 4) {
    STEP(pA, 0)
    STEP(pB, 1)
    STEP(pC, 2)
    STEP(pD, 3)
  }
#undef STEP

  float m = fminf(fminf(m0, m1), fminf(m2, m3));

  // lanes l and l^32 cover complementary rows for the same query column
  m = fminf(m, __shfl_xor(m, 32));
  float rq = qr[q];
  float dmin = fmaxf(rq + m, 0.f);
  float v = (lane < 32) ? dmin : 0.f;
  for (int o = 1; o < 32; o <<= 1) v += __shfl_xor(v, o);
  if (lane == 0) wsum[wv] = v;
  __syncthreads();
  if (tid == 0) part[blockIdx.x] = wsum[0] + wsum[1] + wsum[2] + wsum[3];
}

// ---------------- final reduce ----------------
__global__ void final_kernel(const float* __restrict__ part_noise,
                             const float* __restrict__ part_cham,
                             float* __restrict__ out) {
  __shared__ float red[256];
  float s = 0.f;
  for (int i = threadIdx.x; i < PACK_BLOCKS; i += 256) s += part_noise[i];
  float t = 0.f;
  for (int i = threadIdx.x; i < CHAM_BLOCKS; i += 256) t += part_cham[i];
  red[threadIdx.x] = s; __syncthreads();
  for (int o = 128; o; o >>= 1) { if (threadIdx.x < o) red[threadIdx.x] += red[threadIdx.x + o]; __syncthreads(); }
  float noise_sum = red[0];
  __syncthreads();
  red[threadIdx.x] = t; __syncthreads();
  for (int o = 128; o; o >>= 1) { if (threadIdx.x < o) red[threadIdx.x] += red[threadIdx.x + o]; __syncthreads(); }
  if (threadIdx.x == 0)
    out[0] = noise_sum * (1.f / NOISE_N) + 0.1f * red[0] * (1.f / NPTS_TOT);
}

extern "C" void kernel_launch(void* const* d_in, const int* in_sizes, int n_in,
                              void* d_out, int out_size, void* d_ws, size_t ws_size,
                              hipStream_t stream) {
  const float* pn = (const float*)d_in[0];
  const float* an = (const float*)d_in[1];
  const float* pp = (const float*)d_in[2];
  const float* tp = (const float*)d_in[3];

  char* ws = (char*)d_ws;
  float*   noise_part = (float*)(ws + WS_NOISE_PART);
  float*   cham_part  = (float*)(ws + WS_CHAM_PART);
  ushort4* pk_pred    = (ushort4*)(ws + WS_PK_PRED);
  ushort4* pk_targ    = (ushort4*)(ws + WS_PK_TARG);
  float*   r_pred     = (float*)(ws + WS_R_PRED);
  float*   r_targ     = (float*)(ws + WS_R_TARG);

  pack_noise_kernel<<<PACK_BLOCKS, 256, 0, stream>>>(pp, tp, (const float4*)pn, (const float4*)an,
                                                     pk_pred, pk_targ, r_pred, r_targ, noise_part);
  chamfer_kernel<<<CHAM_BLOCKS, 256, 0, stream>>>(pk_pred, pk_targ, r_pred, r_targ, cham_part);
  final_kernel<<<1, 256, 0, stream>>>(noise_part, cham_part, (float*)d_out);
}